// Round 5
// baseline (193.302 us; speedup 1.0000x reference)
//
#include <hip/hip_runtime.h>
#include <stdint.h>

#define LOG2E 1.4426950408889634f

typedef __bf16 v8bf __attribute__((ext_vector_type(8)));
typedef float v16f __attribute__((ext_vector_type(16)));

static constexpr int B = 4, N = 2048, FIN = 128, H = 4, DK = 32;
static constexpr int IT = N / 32;   // 64 i-tiles
static constexpr int PACK_BLOCKS = B * N * N / 1024;          // 16384 (256 thr = 4 waves x 256 ints)
static constexpr int PREP_BLOCKS = (B * N * FIN + H * DK * FIN) / 256;  // 4160

__device__ __forceinline__ float exp2_fast(float x) {
#if __has_builtin(__builtin_amdgcn_exp2f)
  return __builtin_amdgcn_exp2f(x);
#else
  float r;
  asm("v_exp_f32 %0, %1" : "=v"(r) : "v"(x));
  return r;
#endif
}

__device__ __forceinline__ unsigned int bf16_rne(float f) {
  unsigned int u = __builtin_bit_cast(unsigned int, f);
  u += 0x7FFFu + ((u >> 16) & 1u);
  return u >> 16;
}

// ------- kernel 0 (merged): adj bit-pack + x->bf16 cast + wtb[h][d][f] bf16 -------
__global__ __launch_bounds__(256) void k_prep(const int* __restrict__ adj,
                                              const float* __restrict__ x,
                                              const float* __restrict__ W,
                                              unsigned int* __restrict__ adjb,
                                              unsigned short* __restrict__ xb,
                                              unsigned short* __restrict__ wtb) {
  int bid = blockIdx.x;
  int tid = threadIdx.x;
  if (bid < PACK_BLOCKS) {
    int wid = (bid * 256 + tid) >> 6;      // global wave id, 256 consecutive ints each
    int lane = tid & 63;
    const int* p = adj + (size_t)wid * 256 + lane;
    unsigned long long m0 = __ballot(p[0] != 0);
    unsigned long long m1 = __ballot(p[64] != 0);
    unsigned long long m2 = __ballot(p[128] != 0);
    unsigned long long m3 = __ballot(p[192] != 0);
    if (lane == 0) {
      uint4 v0 = {(unsigned)m0, (unsigned)(m0 >> 32), (unsigned)m1, (unsigned)(m1 >> 32)};
      uint4 v1 = {(unsigned)m2, (unsigned)(m2 >> 32), (unsigned)m3, (unsigned)(m3 >> 32)};
      uint4* dst = (uint4*)(adjb + (size_t)wid * 8);
      dst[0] = v0;
      dst[1] = v1;
    }
    return;
  }
  int idx = (bid - PACK_BLOCKS) * 256 + tid;
  constexpr int TX = B * N * FIN;          // 1048576
  if (idx < TX) {
    xb[idx] = (unsigned short)bf16_rne(x[idx]);
  } else {
    int j = idx - TX;                      // < H*DK*FIN = 16384
    int h = j >> 12, r = j & 4095, d = r >> 7, f = r & 127;
    wtb[j] = (unsigned short)bf16_rne(W[(h * FIN + f) * DK + d]);
  }
}

// ------- kernel 1: h projection via dual MFMA; h_frag (fragment order) + el/er -------
// acc  = mfma(w,x): D[d][n] -> el/er epilogue (unchanged orientation)
// accd = mfma(x,w): D[n][d] -> h stored in MFMA-B-fragment order, coalesced:
//   h_frag[bh][jblk][lane][e] with k-permutation pi(kh,e) = 4*kh + (e&3) + 8*(e>>2)
__global__ __launch_bounds__(256) void k_hproj(const unsigned short* __restrict__ xb,
                                               const unsigned short* __restrict__ wtb,
                                               const float* __restrict__ a,
                                               unsigned short* __restrict__ h_frag,
                                               float* __restrict__ el,
                                               float* __restrict__ er) {
  int blk = blockIdx.x;
  int b = blk >> 6, it = blk & 63;
  int tid = threadIdx.x;
  int head = tid >> 6, lane = tid & 63;
  int lrow = lane & 31, kh = lane >> 5;
  int bh = b * H + head;
  int n = it * 32 + lrow;
  const unsigned short* xp = xb + (b * N + n) * FIN + kh * 8;
  const unsigned short* wp = wtb + (head * DK + lrow) * FIN + kh * 8;
  v16f acc = {};    // D[d][n], col=n=lrow
  v16f accd = {};   // D[n][d], col=d=lrow
#pragma unroll
  for (int s = 0; s < FIN / 16; ++s) {
    v8bf av = __builtin_bit_cast(v8bf, *(const int4*)(wp + s * 16));
    v8bf bv = __builtin_bit_cast(v8bf, *(const int4*)(xp + s * 16));
    acc = __builtin_amdgcn_mfma_f32_32x32x16_bf16(av, bv, acc, 0, 0, 0);
    accd = __builtin_amdgcn_mfma_f32_32x32x16_bf16(bv, av, accd, 0, 0, 0);
  }
  // h_frag: thread holds h[n = (r&3)+8*(r>>2)+4*kh][d = lrow] for r=0..15.
  // r=0..7 -> n in [0,16) -> jblk it*2 ; r=8..15 -> jblk it*2+1. frag lane = kh*32+d = lane.
  {
    unsigned w[8];
#pragma unroll
    for (int i = 0; i < 8; ++i)
      w[i] = bf16_rne(accd[2 * i]) | (bf16_rne(accd[2 * i + 1]) << 16);
    unsigned short* fp = h_frag + (((size_t)bh * 128 + it * 2) * 64 + lane) * 8;
    int4 v0 = {(int)w[0], (int)w[1], (int)w[2], (int)w[3]};
    int4 v1 = {(int)w[4], (int)w[5], (int)w[6], (int)w[7]};
    *(int4*)fp = v0;
    *(int4*)(fp + 512) = v1;   // next jblk: +64 lanes * 8 shorts
  }
  float pel = 0.f, per = 0.f;
#pragma unroll
  for (int r = 0; r < 16; ++r) {
    int d = (r & 3) + 8 * (r >> 2) + 4 * kh;   // C/D row mapping (32x32 bf16)
    float hv = acc[r];
    pel = fmaf(hv, a[head * 2 * DK + d], pel);
    per = fmaf(hv, a[head * 2 * DK + DK + d], per);
  }
  pel += __shfl_xor(pel, 32);
  per += __shfl_xor(per, 32);
  if (kh == 0) {
    el[bh * N + n] = pel * LOG2E;
    er[bh * N + n] = per * LOG2E;
  }
}

// ---------------- kernel 2: fused attention over a j-half, partials to ws ----------------
// grid = B*IT*2; block = 1024 threads = 16 waves = (jq 0..3) x (head 0..3)
// h loads now COALESCED (fragment-order h_frag, 1KB/wave-load); er staged in LDS;
// A-side P built with matching k-permutation pi(kh,e) = 4*kh + (e&3) + 8*(e>>2).
__global__ __launch_bounds__(1024, 8) void k_attn(const unsigned int* __restrict__ adjb,
                                                  const unsigned short* __restrict__ h_frag,
                                                  const float* __restrict__ el,
                                                  const float* __restrict__ er,
                                                  float* __restrict__ pnum,
                                                  float* __restrict__ pden) {
  __shared__ __align__(16) float part4[4][H][1024];  // 64KB; part4[0] aliased as er stage in loop
  __shared__ float lsh4[4][H][32];      // [jq][head][i]
  int blk = blockIdx.x;                 // 0..511
  int bit = blk >> 1, jh = blk & 1;
  int b = bit >> 6, it = bit & 63;
  int tid = threadIdx.x;
  int wave = tid >> 6;
  int head = wave & 3, jq = wave >> 2;
  int lane = tid & 63, lrow = lane & 31, kh = lane >> 5;
  int ig = it * 32 + lrow, bh = b * H + head;

  // stage this j-half's er for all 4 heads into LDS: 4096 floats, 4/thread, coalesced
  {
    int hh = tid >> 8, jl = (tid & 255) * 4;
    *(float4*)&part4[0][hh][jl] = *(const float4*)&er[(b * H + hh) * N + jh * 1024 + jl];
  }

  float eli = el[bh * N + ig];
  // coalesced fragment pointer: jblk = jh*64 + jq*16 + s ; 512 shorts per s
  const unsigned short* hp =
      h_frag + (((size_t)bh * 128 + jh * 64 + jq * 16) * 64 + lane) * 8;
  int jql = jq * 256 + 4 * kh;          // er LDS base (k-permuted)

  // this lane's adjacency bits for its 256-j quarter (one-time latency, L2-resident)
  const uint4* abp = (const uint4*)(adjb + (size_t)(b * N + ig) * 64 + jh * 32 + jq * 8);
  uint4 ab0 = abp[0], ab1 = abp[1];
  unsigned adw[8] = {ab0.x, ab0.y, ab0.z, ab0.w, ab1.x, ab1.y, ab1.z, ab1.w};
  int shkh = kh * 4;

  // h prefetch, 2 deep (issued before barrier: global, no LDS dependency)
  int4 hreg0 = *(const int4*)hp;
  int4 hreg1 = *(const int4*)(hp + 512);

  __syncthreads();   // er stage visible

  v16f acc = {};
  float lsum = 0.f;
  float4 Ea = *(const float4*)&part4[0][head][jql];        // LDS, s=0
  float4 Eb = *(const float4*)&part4[0][head][jql + 8];
#pragma unroll
  for (int s = 0; s < 16; ++s) {
    int4 hb = (s & 1) ? hreg1 : hreg0;
    if (s + 2 < 16) {
      int4 nv = *(const int4*)(hp + (s + 2) * 512);
      if (s & 1) hreg1 = nv; else hreg0 = nv;
    }
    float4 ea = Ea, eb = Eb;
    if (s + 1 < 16) {
      Ea = *(const float4*)&part4[0][head][jql + (s + 1) * 16];
      Eb = *(const float4*)&part4[0][head][jql + (s + 1) * 16 + 8];
    }
    // bits for slots e: j-offset = s*16 + 4*kh + (e&3) + 8*(e>>2)
    unsigned mb = (adw[s >> 1] >> (((s & 1) * 16) + shkh)) & 0xF0Fu;
    float ev[8] = {ea.x, ea.y, ea.z, ea.w, eb.x, eb.y, eb.z, eb.w};
    const unsigned mtab[8] = {1u, 2u, 4u, 8u, 0x100u, 0x200u, 0x400u, 0x800u};
    unsigned ub[8];
#pragma unroll
    for (int k = 0; k < 8; ++k) {
      float tt = eli + ev[k];
      tt = fmaxf(tt, 0.2f * tt);            // leaky relu (log2e pre-folded)
      float pv = exp2_fast(tt);
      unsigned u = __builtin_bit_cast(unsigned, pv) & 0xFFFF0000u;
      u = (mb & mtab[k]) ? u : 0u;          // adjacency bit mask (permuted slot)
      ub[k] = u;
      lsum += __builtin_bit_cast(float, u); // truncated value: num/den consistent
    }
    unsigned u0 = __builtin_amdgcn_perm(ub[1], ub[0], 0x07060302u);
    unsigned u1 = __builtin_amdgcn_perm(ub[3], ub[2], 0x07060302u);
    unsigned u2 = __builtin_amdgcn_perm(ub[5], ub[4], 0x07060302u);
    unsigned u3 = __builtin_amdgcn_perm(ub[7], ub[6], 0x07060302u);
    uint4 au = {u0, u1, u2, u3};
    v8bf av = __builtin_bit_cast(v8bf, au);
    v8bf hv = __builtin_bit_cast(v8bf, hb);
    acc = __builtin_amdgcn_mfma_f32_32x32x16_bf16(av, hv, acc, 0, 0, 0);
  }

  lsum += __shfl_xor(lsum, 32);
  if (lane < 32) lsh4[jq][head][lane] = lsum;   // lsh4 separate: safe before barrier

  __syncthreads();   // all er LDS reads done before part4 overwrite

#pragma unroll
  for (int r = 0; r < 16; ++r) {
    int rowl = (r & 3) + 8 * (r >> 2) + 4 * kh;   // i-row within tile
    part4[jq][head][rowl * 32 + lrow] = acc[r];   // private slice: plain store
  }
  __syncthreads();

  // combine 4 jq slices; 4096 partial outputs / 1024 threads = one float4 each
  int e = tid * 4;
  int rh = e >> 10, rr = e & 1023;
  float4 q0 = *(const float4*)&part4[0][rh][rr];
  float4 q1 = *(const float4*)&part4[1][rh][rr];
  float4 q2 = *(const float4*)&part4[2][rh][rr];
  float4 q3 = *(const float4*)&part4[3][rh][rr];
  float4 s4;
  s4.x = (q0.x + q1.x) + (q2.x + q3.x);
  s4.y = (q0.y + q1.y) + (q2.y + q3.y);
  s4.z = (q0.z + q1.z) + (q2.z + q3.z);
  s4.w = (q0.w + q1.w) + (q2.w + q3.w);
  *(float4*)&pnum[(size_t)blk * 4096 + e] = s4;
  if (tid < 128) {
    float d = (lsh4[0][tid >> 5][tid & 31] + lsh4[1][tid >> 5][tid & 31]) +
              (lsh4[2][tid >> 5][tid & 31] + lsh4[3][tid >> 5][tid & 31]);
    pden[blk * 128 + tid] = d;
  }
}

// ---------------- kernel 3: combine j-halves + normalize ----------------
__global__ __launch_bounds__(1024) void k_final(const float* __restrict__ pnum,
                                                const float* __restrict__ pden,
                                                float* __restrict__ out) {
  int bit = blockIdx.x;            // 0..255 = (b, it)
  int b = bit >> 6, it = bit & 63;
  int tid = threadIdx.x;
  int e = tid * 4;
  int rh = e >> 10, ri = (e >> 5) & 31, rd = e & 31;
  size_t p0 = (size_t)(bit * 2) * 4096 + e;
  float4 n0 = *(const float4*)&pnum[p0];
  float4 n1 = *(const float4*)&pnum[p0 + 4096];
  float d = pden[bit * 2 * 128 + rh * 32 + ri] + pden[(bit * 2 + 1) * 128 + rh * 32 + ri];
  float inv = 1.0f / d;
  float4 o;
  o.x = (n0.x + n1.x) * inv;
  o.y = (n0.y + n1.y) * inv;
  o.z = (n0.z + n1.z) * inv;
  o.w = (n0.w + n1.w) * inv;
  *(float4*)&out[(size_t)((b * H + rh) * N + it * 32 + ri) * DK + rd] = o;
}

extern "C" void kernel_launch(void* const* d_in, const int* in_sizes, int n_in,
                              void* d_out, int out_size, void* d_ws, size_t ws_size,
                              hipStream_t stream) {
  const float* x = (const float*)d_in[0];
  const int* adj = (const int*)d_in[1];
  const float* W = (const float*)d_in[2];
  const float* a = (const float*)d_in[3];
  float* out = (float*)d_out;
  char* ws = (char*)d_ws;

  unsigned short* h_frag = (unsigned short*)(ws);          // 2 MB   [B*H][128 jblk][64][8]
  float* el = (float*)(ws + 0x200000);                     // 128 KB
  float* er = (float*)(ws + 0x220000);                     // 128 KB
  unsigned short* wtb = (unsigned short*)(ws + 0x240000);  // 32 KB
  unsigned int* adjb = (unsigned int*)(ws + 0x250000);     // 2 MB bitmask
  unsigned short* xb = (unsigned short*)(ws + 0x450000);   // 2 MB
  float* pnum = (float*)(ws + 0x650000);                   // 8 MB   [512][H][32][32]
  float* pden = (float*)(ws + 0xE50000);                   // 256 KB [512][H][32]
  // total ~14.8 MB

  hipLaunchKernelGGL(k_prep, dim3(PACK_BLOCKS + PREP_BLOCKS), dim3(256), 0, stream,
                     adj, x, W, adjb, xb, wtb);
  hipLaunchKernelGGL(k_hproj, dim3(B * IT), dim3(256), 0, stream, xb, wtb, a, h_frag, el, er);
  hipLaunchKernelGGL(k_attn, dim3(B * IT * 2), dim3(1024), 0, stream, adjb, h_frag, el, er, pnum, pden);
  hipLaunchKernelGGL(k_final, dim3(B * IT), dim3(1024), 0, stream, pnum, pden, out);
}

// Round 6
// 191.910 us; speedup vs baseline: 1.0073x; 1.0073x over previous
//
#include <hip/hip_runtime.h>
#include <stdint.h>

#define LOG2E 1.4426950408889634f

typedef __bf16 v8bf __attribute__((ext_vector_type(8)));
typedef float v16f __attribute__((ext_vector_type(16)));

static constexpr int B = 4, N = 2048, FIN = 128, H = 4, DK = 32;
static constexpr int IT = N / 32;   // 64 i-tiles
static constexpr int PACK_BLOCKS = B * N * N / 1024;          // 16384 (256 thr = 4 waves x 256 ints)
static constexpr int PREP_BLOCKS = (B * N * FIN + H * DK * FIN) / 256;  // 4160

__device__ __forceinline__ float exp2_fast(float x) {
#if __has_builtin(__builtin_amdgcn_exp2f)
  return __builtin_amdgcn_exp2f(x);
#else
  float r;
  asm("v_exp_f32 %0, %1" : "=v"(r) : "v"(x));
  return r;
#endif
}

__device__ __forceinline__ unsigned int bf16_rne(float f) {
  unsigned int u = __builtin_bit_cast(unsigned int, f);
  u += 0x7FFFu + ((u >> 16) & 1u);
  return u >> 16;
}

// ------- kernel 0 (merged): adj bit-pack + x->bf16 cast + wtb[h][d][f] bf16 -------
__global__ __launch_bounds__(256) void k_prep(const int* __restrict__ adj,
                                              const float* __restrict__ x,
                                              const float* __restrict__ W,
                                              unsigned int* __restrict__ adjb,
                                              unsigned short* __restrict__ xb,
                                              unsigned short* __restrict__ wtb) {
  int bid = blockIdx.x;
  int tid = threadIdx.x;
  if (bid < PACK_BLOCKS) {
    int wid = (bid * 256 + tid) >> 6;      // global wave id, 256 consecutive ints each
    int lane = tid & 63;
    const int* p = adj + (size_t)wid * 256 + lane;
    unsigned long long m0 = __ballot(p[0] != 0);
    unsigned long long m1 = __ballot(p[64] != 0);
    unsigned long long m2 = __ballot(p[128] != 0);
    unsigned long long m3 = __ballot(p[192] != 0);
    if (lane == 0) {
      uint4 v0 = {(unsigned)m0, (unsigned)(m0 >> 32), (unsigned)m1, (unsigned)(m1 >> 32)};
      uint4 v1 = {(unsigned)m2, (unsigned)(m2 >> 32), (unsigned)m3, (unsigned)(m3 >> 32)};
      uint4* dst = (uint4*)(adjb + (size_t)wid * 8);
      dst[0] = v0;
      dst[1] = v1;
    }
    return;
  }
  int idx = (bid - PACK_BLOCKS) * 256 + tid;
  constexpr int TX = B * N * FIN;          // 1048576
  if (idx < TX) {
    xb[idx] = (unsigned short)bf16_rne(x[idx]);
  } else {
    int j = idx - TX;                      // < H*DK*FIN = 16384
    int h = j >> 12, r = j & 4095, d = r >> 7, f = r & 127;
    wtb[j] = (unsigned short)bf16_rne(W[(h * FIN + f) * DK + d]);
  }
}

// ------- kernel 1: h projection via dual MFMA; h_frag (fragment order) + el/er -------
// acc  = mfma(w,x): D[d][n] -> el/er epilogue (unchanged orientation)
// accd = mfma(x,w): D[n][d] -> h stored in MFMA-B-fragment order, coalesced:
//   h_frag[bh][jblk][lane][e] with k-permutation pi(kh,e) = 4*kh + (e&3) + 8*(e>>2)
__global__ __launch_bounds__(256) void k_hproj(const unsigned short* __restrict__ xb,
                                               const unsigned short* __restrict__ wtb,
                                               const float* __restrict__ a,
                                               unsigned short* __restrict__ h_frag,
                                               float* __restrict__ el,
                                               float* __restrict__ er) {
  int blk = blockIdx.x;
  int b = blk >> 6, it = blk & 63;
  int tid = threadIdx.x;
  int head = tid >> 6, lane = tid & 63;
  int lrow = lane & 31, kh = lane >> 5;
  int bh = b * H + head;
  int n = it * 32 + lrow;
  const unsigned short* xp = xb + (b * N + n) * FIN + kh * 8;
  const unsigned short* wp = wtb + (head * DK + lrow) * FIN + kh * 8;
  v16f acc = {};    // D[d][n], col=n=lrow
  v16f accd = {};   // D[n][d], col=d=lrow
#pragma unroll
  for (int s = 0; s < FIN / 16; ++s) {
    v8bf av = __builtin_bit_cast(v8bf, *(const int4*)(wp + s * 16));
    v8bf bv = __builtin_bit_cast(v8bf, *(const int4*)(xp + s * 16));
    acc = __builtin_amdgcn_mfma_f32_32x32x16_bf16(av, bv, acc, 0, 0, 0);
    accd = __builtin_amdgcn_mfma_f32_32x32x16_bf16(bv, av, accd, 0, 0, 0);
  }
  // h_frag: thread holds h[n = (r&3)+8*(r>>2)+4*kh][d = lrow] for r=0..15.
  // r=0..7 -> n in [0,16) -> jblk it*2 ; r=8..15 -> jblk it*2+1. frag lane = kh*32+d = lane.
  {
    unsigned w[8];
#pragma unroll
    for (int i = 0; i < 8; ++i)
      w[i] = bf16_rne(accd[2 * i]) | (bf16_rne(accd[2 * i + 1]) << 16);
    unsigned short* fp = h_frag + (((size_t)bh * 128 + it * 2) * 64 + lane) * 8;
    int4 v0 = {(int)w[0], (int)w[1], (int)w[2], (int)w[3]};
    int4 v1 = {(int)w[4], (int)w[5], (int)w[6], (int)w[7]};
    *(int4*)fp = v0;
    *(int4*)(fp + 512) = v1;   // next jblk: +64 lanes * 8 shorts
  }
  float pel = 0.f, per = 0.f;
#pragma unroll
  for (int r = 0; r < 16; ++r) {
    int d = (r & 3) + 8 * (r >> 2) + 4 * kh;   // C/D row mapping (32x32 bf16)
    float hv = acc[r];
    pel = fmaf(hv, a[head * 2 * DK + d], pel);
    per = fmaf(hv, a[head * 2 * DK + DK + d], per);
  }
  pel += __shfl_xor(pel, 32);
  per += __shfl_xor(per, 32);
  if (kh == 0) {
    el[bh * N + n] = pel * LOG2E;
    er[bh * N + n] = per * LOG2E;
  }
}

// ---------------- kernel 2: fused attention over a j-half, partials to ws ----------------
// grid = B*IT*2; block = 1024 threads = 16 waves = (jq 0..3) x (head 0..3)
// h loads COALESCED (fragment-order h_frag, 1KB/wave-load); er staged in LDS;
// A-side P built with matching k-permutation pi(kh,e) = 4*kh + (e&3) + 8*(e>>2).
// NOTE: no local arrays beyond the register-proven ev/ub/adw (rule #20 — the
// r5 'mtab' const array went to scratch: 320B/thread -> 167MB writebacks).
__global__ __launch_bounds__(1024, 8) void k_attn(const unsigned int* __restrict__ adjb,
                                                  const unsigned short* __restrict__ h_frag,
                                                  const float* __restrict__ el,
                                                  const float* __restrict__ er,
                                                  float* __restrict__ pnum,
                                                  float* __restrict__ pden) {
  __shared__ __align__(16) float part4[4][H][1024];  // 64KB; part4[0] aliased as er stage in loop
  __shared__ float lsh4[4][H][32];      // [jq][head][i]
  int blk = blockIdx.x;                 // 0..511
  int bit = blk >> 1, jh = blk & 1;
  int b = bit >> 6, it = bit & 63;
  int tid = threadIdx.x;
  int wave = tid >> 6;
  int head = wave & 3, jq = wave >> 2;
  int lane = tid & 63, lrow = lane & 31, kh = lane >> 5;
  int ig = it * 32 + lrow, bh = b * H + head;

  // stage this j-half's er for all 4 heads into LDS: 4096 floats, 4/thread, coalesced
  {
    int hh = tid >> 8, jl = (tid & 255) * 4;
    *(float4*)&part4[0][hh][jl] = *(const float4*)&er[(b * H + hh) * N + jh * 1024 + jl];
  }

  float eli = el[bh * N + ig];
  // coalesced fragment pointer: jblk = jh*64 + jq*16 + s ; 512 shorts per s
  const unsigned short* hp =
      h_frag + (((size_t)bh * 128 + jh * 64 + jq * 16) * 64 + lane) * 8;
  int jql = jq * 256 + 4 * kh;          // er LDS base (k-permuted)

  // this lane's adjacency bits for its 256-j quarter (one-time latency, L2-resident)
  const uint4* abp = (const uint4*)(adjb + (size_t)(b * N + ig) * 64 + jh * 32 + jq * 8);
  uint4 ab0 = abp[0], ab1 = abp[1];
  unsigned adw[8] = {ab0.x, ab0.y, ab0.z, ab0.w, ab1.x, ab1.y, ab1.z, ab1.w};
  int shkh = kh * 4;

  // h prefetch, 2 deep (issued before barrier: global, no LDS dependency)
  int4 hreg0 = *(const int4*)hp;
  int4 hreg1 = *(const int4*)(hp + 512);

  __syncthreads();   // er stage visible

  v16f acc = {};
  float lsum = 0.f;
  float4 Ea = *(const float4*)&part4[0][head][jql];        // LDS, s=0
  float4 Eb = *(const float4*)&part4[0][head][jql + 8];
#pragma unroll
  for (int s = 0; s < 16; ++s) {
    int4 hb = (s & 1) ? hreg1 : hreg0;
    if (s + 2 < 16) {
      int4 nv = *(const int4*)(hp + (s + 2) * 512);
      if (s & 1) hreg1 = nv; else hreg0 = nv;
    }
    float4 ea = Ea, eb = Eb;
    if (s + 1 < 16) {
      Ea = *(const float4*)&part4[0][head][jql + (s + 1) * 16];
      Eb = *(const float4*)&part4[0][head][jql + (s + 1) * 16 + 8];
    }
    // bits for slots e: j-offset = s*16 + 4*kh + (e&3) + 8*(e>>2)
    unsigned mb = (adw[s >> 1] >> (((s & 1) * 16) + shkh)) & 0xF0Fu;
    float ev[8] = {ea.x, ea.y, ea.z, ea.w, eb.x, eb.y, eb.z, eb.w};
    unsigned ub[8];
#pragma unroll
    for (int k = 0; k < 8; ++k) {
      float tt = eli + ev[k];
      tt = fmaxf(tt, 0.2f * tt);            // leaky relu (log2e pre-folded)
      float pv = exp2_fast(tt);
      unsigned u = __builtin_bit_cast(unsigned, pv) & 0xFFFF0000u;
      // compile-time constant bit (k unrolled): {1,2,4,8,0x100,0x200,0x400,0x800}
      u = (mb & (1u << ((k & 3) + 8 * (k >> 2)))) ? u : 0u;
      ub[k] = u;
      lsum += __builtin_bit_cast(float, u); // truncated value: num/den consistent
    }
    unsigned u0 = __builtin_amdgcn_perm(ub[1], ub[0], 0x07060302u);
    unsigned u1 = __builtin_amdgcn_perm(ub[3], ub[2], 0x07060302u);
    unsigned u2 = __builtin_amdgcn_perm(ub[5], ub[4], 0x07060302u);
    unsigned u3 = __builtin_amdgcn_perm(ub[7], ub[6], 0x07060302u);
    uint4 au = {u0, u1, u2, u3};
    v8bf av = __builtin_bit_cast(v8bf, au);
    v8bf hv = __builtin_bit_cast(v8bf, hb);
    acc = __builtin_amdgcn_mfma_f32_32x32x16_bf16(av, hv, acc, 0, 0, 0);
  }

  lsum += __shfl_xor(lsum, 32);
  if (lane < 32) lsh4[jq][head][lane] = lsum;   // lsh4 separate: safe before barrier

  __syncthreads();   // all er LDS reads done before part4 overwrite

#pragma unroll
  for (int r = 0; r < 16; ++r) {
    int rowl = (r & 3) + 8 * (r >> 2) + 4 * kh;   // i-row within tile
    part4[jq][head][rowl * 32 + lrow] = acc[r];   // private slice: plain store
  }
  __syncthreads();

  // combine 4 jq slices; 4096 partial outputs / 1024 threads = one float4 each
  int e = tid * 4;
  int rh = e >> 10, rr = e & 1023;
  float4 q0 = *(const float4*)&part4[0][rh][rr];
  float4 q1 = *(const float4*)&part4[1][rh][rr];
  float4 q2 = *(const float4*)&part4[2][rh][rr];
  float4 q3 = *(const float4*)&part4[3][rh][rr];
  float4 s4;
  s4.x = (q0.x + q1.x) + (q2.x + q3.x);
  s4.y = (q0.y + q1.y) + (q2.y + q3.y);
  s4.z = (q0.z + q1.z) + (q2.z + q3.z);
  s4.w = (q0.w + q1.w) + (q2.w + q3.w);
  *(float4*)&pnum[(size_t)blk * 4096 + e] = s4;
  if (tid < 128) {
    float d = (lsh4[0][tid >> 5][tid & 31] + lsh4[1][tid >> 5][tid & 31]) +
              (lsh4[2][tid >> 5][tid & 31] + lsh4[3][tid >> 5][tid & 31]);
    pden[blk * 128 + tid] = d;
  }
}

// ---------------- kernel 3: combine j-halves + normalize ----------------
__global__ __launch_bounds__(1024) void k_final(const float* __restrict__ pnum,
                                                const float* __restrict__ pden,
                                                float* __restrict__ out) {
  int bit = blockIdx.x;            // 0..255 = (b, it)
  int b = bit >> 6, it = bit & 63;
  int tid = threadIdx.x;
  int e = tid * 4;
  int rh = e >> 10, ri = (e >> 5) & 31, rd = e & 31;
  size_t p0 = (size_t)(bit * 2) * 4096 + e;
  float4 n0 = *(const float4*)&pnum[p0];
  float4 n1 = *(const float4*)&pnum[p0 + 4096];
  float d = pden[bit * 2 * 128 + rh * 32 + ri] + pden[(bit * 2 + 1) * 128 + rh * 32 + ri];
  float inv = 1.0f / d;
  float4 o;
  o.x = (n0.x + n1.x) * inv;
  o.y = (n0.y + n1.y) * inv;
  o.z = (n0.z + n1.z) * inv;
  o.w = (n0.w + n1.w) * inv;
  *(float4*)&out[(size_t)((b * H + rh) * N + it * 32 + ri) * DK + rd] = o;
}

extern "C" void kernel_launch(void* const* d_in, const int* in_sizes, int n_in,
                              void* d_out, int out_size, void* d_ws, size_t ws_size,
                              hipStream_t stream) {
  const float* x = (const float*)d_in[0];
  const int* adj = (const int*)d_in[1];
  const float* W = (const float*)d_in[2];
  const float* a = (const float*)d_in[3];
  float* out = (float*)d_out;
  char* ws = (char*)d_ws;

  unsigned short* h_frag = (unsigned short*)(ws);          // 2 MB   [B*H][128 jblk][64][8]
  float* el = (float*)(ws + 0x200000);                     // 128 KB
  float* er = (float*)(ws + 0x220000);                     // 128 KB
  unsigned short* wtb = (unsigned short*)(ws + 0x240000);  // 32 KB
  unsigned int* adjb = (unsigned int*)(ws + 0x250000);     // 2 MB bitmask
  unsigned short* xb = (unsigned short*)(ws + 0x450000);   // 2 MB
  float* pnum = (float*)(ws + 0x650000);                   // 8 MB   [512][H][32][32]
  float* pden = (float*)(ws + 0xE50000);                   // 256 KB [512][H][32]
  // total ~14.8 MB

  hipLaunchKernelGGL(k_prep, dim3(PACK_BLOCKS + PREP_BLOCKS), dim3(256), 0, stream,
                     adj, x, W, adjb, xb, wtb);
  hipLaunchKernelGGL(k_hproj, dim3(B * IT), dim3(256), 0, stream, xb, wtb, a, h_frag, el, er);
  hipLaunchKernelGGL(k_attn, dim3(B * IT * 2), dim3(1024), 0, stream, adjb, h_frag, el, er, pnum, pden);
  hipLaunchKernelGGL(k_final, dim3(B * IT), dim3(1024), 0, stream, pnum, pden, out);
}

// Round 7
// 131.719 us; speedup vs baseline: 1.4675x; 1.4570x over previous
//
#include <hip/hip_runtime.h>
#include <stdint.h>

#define LOG2E 1.4426950408889634f

typedef __bf16 v8bf __attribute__((ext_vector_type(8)));
typedef float v16f __attribute__((ext_vector_type(16)));

static constexpr int B = 4, N = 2048, FIN = 128, H = 4, DK = 32;
static constexpr int IT = N / 32;   // 64 i-tiles
static constexpr int PACK_BLOCKS = B * N * N / 1024;          // 16384 (256 thr = 4 waves x 256 ints)
static constexpr int PREP_BLOCKS = (B * N * FIN + H * DK * FIN) / 256;  // 4160

__device__ __forceinline__ float exp2_fast(float x) {
#if __has_builtin(__builtin_amdgcn_exp2f)
  return __builtin_amdgcn_exp2f(x);
#else
  float r;
  asm("v_exp_f32 %0, %1" : "=v"(r) : "v"(x));
  return r;
#endif
}

__device__ __forceinline__ unsigned int bf16_rne(float f) {
  unsigned int u = __builtin_bit_cast(unsigned int, f);
  u += 0x7FFFu + ((u >> 16) & 1u);
  return u >> 16;
}

// ------- kernel 0 (merged): adj bit-pack + x->bf16 cast + wtb[h][d][f] bf16 -------
__global__ __launch_bounds__(256) void k_prep(const int* __restrict__ adj,
                                              const float* __restrict__ x,
                                              const float* __restrict__ W,
                                              unsigned int* __restrict__ adjb,
                                              unsigned short* __restrict__ xb,
                                              unsigned short* __restrict__ wtb) {
  int bid = blockIdx.x;
  int tid = threadIdx.x;
  if (bid < PACK_BLOCKS) {
    int wid = (bid * 256 + tid) >> 6;      // global wave id, 256 consecutive ints each
    int lane = tid & 63;
    const int* p = adj + (size_t)wid * 256 + lane;
    unsigned long long m0 = __ballot(p[0] != 0);
    unsigned long long m1 = __ballot(p[64] != 0);
    unsigned long long m2 = __ballot(p[128] != 0);
    unsigned long long m3 = __ballot(p[192] != 0);
    if (lane == 0) {
      uint4 v0 = {(unsigned)m0, (unsigned)(m0 >> 32), (unsigned)m1, (unsigned)(m1 >> 32)};
      uint4 v1 = {(unsigned)m2, (unsigned)(m2 >> 32), (unsigned)m3, (unsigned)(m3 >> 32)};
      uint4* dst = (uint4*)(adjb + (size_t)wid * 8);
      dst[0] = v0;
      dst[1] = v1;
    }
    return;
  }
  int idx = (bid - PACK_BLOCKS) * 256 + tid;
  constexpr int TX = B * N * FIN;          // 1048576
  if (idx < TX) {
    xb[idx] = (unsigned short)bf16_rne(x[idx]);
  } else {
    int j = idx - TX;                      // < H*DK*FIN = 16384
    int h = j >> 12, r = j & 4095, d = r >> 7, f = r & 127;
    wtb[j] = (unsigned short)bf16_rne(W[(h * FIN + f) * DK + d]);
  }
}

// ------- kernel 1: h projection via dual MFMA; h_frag (fragment order) + el/er -------
// acc  = mfma(w,x): D[d][n] -> el/er epilogue (unchanged orientation)
// accd = mfma(x,w): D[n][d] -> h stored in MFMA-B-fragment order, coalesced:
//   h_frag[bh][jblk][lane][e] with k-permutation pi(kh,e) = 4*kh + (e&3) + 8*(e>>2)
__global__ __launch_bounds__(256) void k_hproj(const unsigned short* __restrict__ xb,
                                               const unsigned short* __restrict__ wtb,
                                               const float* __restrict__ a,
                                               unsigned short* __restrict__ h_frag,
                                               float* __restrict__ el,
                                               float* __restrict__ er) {
  int blk = blockIdx.x;
  int b = blk >> 6, it = blk & 63;
  int tid = threadIdx.x;
  int head = tid >> 6, lane = tid & 63;
  int lrow = lane & 31, kh = lane >> 5;
  int bh = b * H + head;
  int n = it * 32 + lrow;
  const unsigned short* xp = xb + (b * N + n) * FIN + kh * 8;
  const unsigned short* wp = wtb + (head * DK + lrow) * FIN + kh * 8;
  v16f acc = {};    // D[d][n], col=n=lrow
  v16f accd = {};   // D[n][d], col=d=lrow
#pragma unroll
  for (int s = 0; s < FIN / 16; ++s) {
    v8bf av = __builtin_bit_cast(v8bf, *(const int4*)(wp + s * 16));
    v8bf bv = __builtin_bit_cast(v8bf, *(const int4*)(xp + s * 16));
    acc = __builtin_amdgcn_mfma_f32_32x32x16_bf16(av, bv, acc, 0, 0, 0);
    accd = __builtin_amdgcn_mfma_f32_32x32x16_bf16(bv, av, accd, 0, 0, 0);
  }
  // h_frag: thread holds h[n = (r&3)+8*(r>>2)+4*kh][d = lrow] for r=0..15.
  // r=0..7 -> n in [0,16) -> jblk it*2 ; r=8..15 -> jblk it*2+1. frag lane = kh*32+d = lane.
  {
    unsigned w[8];
#pragma unroll
    for (int i = 0; i < 8; ++i)
      w[i] = bf16_rne(accd[2 * i]) | (bf16_rne(accd[2 * i + 1]) << 16);
    unsigned short* fp = h_frag + (((size_t)bh * 128 + it * 2) * 64 + lane) * 8;
    int4 v0 = {(int)w[0], (int)w[1], (int)w[2], (int)w[3]};
    int4 v1 = {(int)w[4], (int)w[5], (int)w[6], (int)w[7]};
    *(int4*)fp = v0;
    *(int4*)(fp + 512) = v1;   // next jblk: +64 lanes * 8 shorts
  }
  float pel = 0.f, per = 0.f;
#pragma unroll
  for (int r = 0; r < 16; ++r) {
    int d = (r & 3) + 8 * (r >> 2) + 4 * kh;   // C/D row mapping (32x32 bf16)
    float hv = acc[r];
    pel = fmaf(hv, a[head * 2 * DK + d], pel);
    per = fmaf(hv, a[head * 2 * DK + DK + d], per);
  }
  pel += __shfl_xor(pel, 32);
  per += __shfl_xor(per, 32);
  if (kh == 0) {
    el[bh * N + n] = pel * LOG2E;
    er[bh * N + n] = per * LOG2E;
  }
}

// ---------------- kernel 2: fused attention over a j-half, partials to ws ----------------
// grid = B*IT*2; block = 1024 threads = 16 waves = (jq 0..3) x (head 0..3)
// h loads COALESCED (fragment-order h_frag, 1KB/wave-load); er staged in LDS.
// launch_bounds(1024, 4): the 1KB-stride prefetch addresses don't fold into the
// 13-bit global-load immediate; at (1024,8)'s 64-VGPR cap the hoisted addresses
// spilled to scratch (~280B/thread -> 147MB WRITE_SIZE, r4-r6). 128-VGPR budget
// eliminates the spill; occupancy drops to 1 block/CU (acceptable: only 1
// coalesced VMEM/iter of latency left to hide).
__global__ __launch_bounds__(1024, 4) void k_attn(const unsigned int* __restrict__ adjb,
                                                  const unsigned short* __restrict__ h_frag,
                                                  const float* __restrict__ el,
                                                  const float* __restrict__ er,
                                                  float* __restrict__ pnum,
                                                  float* __restrict__ pden) {
  __shared__ __align__(16) float part4[4][H][1024];  // 64KB; part4[0] aliased as er stage in loop
  __shared__ float lsh4[4][H][32];      // [jq][head][i]
  int blk = blockIdx.x;                 // 0..511
  int bit = blk >> 1, jh = blk & 1;
  int b = bit >> 6, it = bit & 63;
  int tid = threadIdx.x;
  int wave = tid >> 6;
  int head = wave & 3, jq = wave >> 2;
  int lane = tid & 63, lrow = lane & 31, kh = lane >> 5;
  int ig = it * 32 + lrow, bh = b * H + head;

  // stage this j-half's er for all 4 heads into LDS: 4096 floats, 4/thread, coalesced
  {
    int hh = tid >> 8, jl = (tid & 255) * 4;
    *(float4*)&part4[0][hh][jl] = *(const float4*)&er[(b * H + hh) * N + jh * 1024 + jl];
  }

  float eli = el[bh * N + ig];
  // coalesced fragment pointer: jblk = jh*64 + jq*16 + s ; 512 shorts per s
  const unsigned short* hp =
      h_frag + (((size_t)bh * 128 + jh * 64 + jq * 16) * 64 + lane) * 8;
  int jql = jq * 256 + 4 * kh;          // er LDS base (k-permuted)

  // this lane's adjacency bits for its 256-j quarter (one-time latency, L2-resident)
  const uint4* abp = (const uint4*)(adjb + (size_t)(b * N + ig) * 64 + jh * 32 + jq * 8);
  uint4 ab0 = abp[0], ab1 = abp[1];
  unsigned adw[8] = {ab0.x, ab0.y, ab0.z, ab0.w, ab1.x, ab1.y, ab1.z, ab1.w};
  int shkh = kh * 4;

  // h prefetch, 2 deep (issued before barrier: global, no LDS dependency)
  int4 hreg0 = *(const int4*)hp;
  int4 hreg1 = *(const int4*)(hp + 512);

  __syncthreads();   // er stage visible

  v16f acc = {};
  float lsum = 0.f;
  float4 Ea = *(const float4*)&part4[0][head][jql];        // LDS, s=0
  float4 Eb = *(const float4*)&part4[0][head][jql + 8];
#pragma unroll
  for (int s = 0; s < 16; ++s) {
    int4 hb = (s & 1) ? hreg1 : hreg0;
    if (s + 2 < 16) {
      int4 nv = *(const int4*)(hp + (s + 2) * 512);
      if (s & 1) hreg1 = nv; else hreg0 = nv;
    }
    float4 ea = Ea, eb = Eb;
    if (s + 1 < 16) {
      Ea = *(const float4*)&part4[0][head][jql + (s + 1) * 16];
      Eb = *(const float4*)&part4[0][head][jql + (s + 1) * 16 + 8];
    }
    // bits for slots e: j-offset = s*16 + 4*kh + (e&3) + 8*(e>>2)
    unsigned mb = (adw[s >> 1] >> (((s & 1) * 16) + shkh)) & 0xF0Fu;
    float ev[8] = {ea.x, ea.y, ea.z, ea.w, eb.x, eb.y, eb.z, eb.w};
    unsigned ub[8];
#pragma unroll
    for (int k = 0; k < 8; ++k) {
      float tt = eli + ev[k];
      tt = fmaxf(tt, 0.2f * tt);            // leaky relu (log2e pre-folded)
      float pv = exp2_fast(tt);
      unsigned u = __builtin_bit_cast(unsigned, pv) & 0xFFFF0000u;
      // compile-time constant bit (k unrolled): {1,2,4,8,0x100,0x200,0x400,0x800}
      u = (mb & (1u << ((k & 3) + 8 * (k >> 2)))) ? u : 0u;
      ub[k] = u;
      lsum += __builtin_bit_cast(float, u); // truncated value: num/den consistent
    }
    unsigned u0 = __builtin_amdgcn_perm(ub[1], ub[0], 0x07060302u);
    unsigned u1 = __builtin_amdgcn_perm(ub[3], ub[2], 0x07060302u);
    unsigned u2 = __builtin_amdgcn_perm(ub[5], ub[4], 0x07060302u);
    unsigned u3 = __builtin_amdgcn_perm(ub[7], ub[6], 0x07060302u);
    uint4 au = {u0, u1, u2, u3};
    v8bf av = __builtin_bit_cast(v8bf, au);
    v8bf hv = __builtin_bit_cast(v8bf, hb);
    acc = __builtin_amdgcn_mfma_f32_32x32x16_bf16(av, hv, acc, 0, 0, 0);
  }

  lsum += __shfl_xor(lsum, 32);
  if (lane < 32) lsh4[jq][head][lane] = lsum;   // lsh4 separate: safe before barrier

  __syncthreads();   // all er LDS reads done before part4 overwrite

#pragma unroll
  for (int r = 0; r < 16; ++r) {
    int rowl = (r & 3) + 8 * (r >> 2) + 4 * kh;   // i-row within tile
    part4[jq][head][rowl * 32 + lrow] = acc[r];   // private slice: plain store
  }
  __syncthreads();

  // combine 4 jq slices; 4096 partial outputs / 1024 threads = one float4 each
  int e = tid * 4;
  int rh = e >> 10, rr = e & 1023;
  float4 q0 = *(const float4*)&part4[0][rh][rr];
  float4 q1 = *(const float4*)&part4[1][rh][rr];
  float4 q2 = *(const float4*)&part4[2][rh][rr];
  float4 q3 = *(const float4*)&part4[3][rh][rr];
  float4 s4;
  s4.x = (q0.x + q1.x) + (q2.x + q3.x);
  s4.y = (q0.y + q1.y) + (q2.y + q3.y);
  s4.z = (q0.z + q1.z) + (q2.z + q3.z);
  s4.w = (q0.w + q1.w) + (q2.w + q3.w);
  *(float4*)&pnum[(size_t)blk * 4096 + e] = s4;
  if (tid < 128) {
    float d = (lsh4[0][tid >> 5][tid & 31] + lsh4[1][tid >> 5][tid & 31]) +
              (lsh4[2][tid >> 5][tid & 31] + lsh4[3][tid >> 5][tid & 31]);
    pden[blk * 128 + tid] = d;
  }
}

// ---------------- kernel 3: combine j-halves + normalize ----------------
__global__ __launch_bounds__(1024) void k_final(const float* __restrict__ pnum,
                                                const float* __restrict__ pden,
                                                float* __restrict__ out) {
  int bit = blockIdx.x;            // 0..255 = (b, it)
  int b = bit >> 6, it = bit & 63;
  int tid = threadIdx.x;
  int e = tid * 4;
  int rh = e >> 10, ri = (e >> 5) & 31, rd = e & 31;
  size_t p0 = (size_t)(bit * 2) * 4096 + e;
  float4 n0 = *(const float4*)&pnum[p0];
  float4 n1 = *(const float4*)&pnum[p0 + 4096];
  float d = pden[bit * 2 * 128 + rh * 32 + ri] + pden[(bit * 2 + 1) * 128 + rh * 32 + ri];
  float inv = 1.0f / d;
  float4 o;
  o.x = (n0.x + n1.x) * inv;
  o.y = (n0.y + n1.y) * inv;
  o.z = (n0.z + n1.z) * inv;
  o.w = (n0.w + n1.w) * inv;
  *(float4*)&out[(size_t)((b * H + rh) * N + it * 32 + ri) * DK + rd] = o;
}

extern "C" void kernel_launch(void* const* d_in, const int* in_sizes, int n_in,
                              void* d_out, int out_size, void* d_ws, size_t ws_size,
                              hipStream_t stream) {
  const float* x = (const float*)d_in[0];
  const int* adj = (const int*)d_in[1];
  const float* W = (const float*)d_in[2];
  const float* a = (const float*)d_in[3];
  float* out = (float*)d_out;
  char* ws = (char*)d_ws;

  unsigned short* h_frag = (unsigned short*)(ws);          // 2 MB   [B*H][128 jblk][64][8]
  float* el = (float*)(ws + 0x200000);                     // 128 KB
  float* er = (float*)(ws + 0x220000);                     // 128 KB
  unsigned short* wtb = (unsigned short*)(ws + 0x240000);  // 32 KB
  unsigned int* adjb = (unsigned int*)(ws + 0x250000);     // 2 MB bitmask
  unsigned short* xb = (unsigned short*)(ws + 0x450000);   // 2 MB
  float* pnum = (float*)(ws + 0x650000);                   // 8 MB   [512][H][32][32]
  float* pden = (float*)(ws + 0xE50000);                   // 256 KB [512][H][32]
  // total ~14.8 MB

  hipLaunchKernelGGL(k_prep, dim3(PACK_BLOCKS + PREP_BLOCKS), dim3(256), 0, stream,
                     adj, x, W, adjb, xb, wtb);
  hipLaunchKernelGGL(k_hproj, dim3(B * IT), dim3(256), 0, stream, xb, wtb, a, h_frag, el, er);
  hipLaunchKernelGGL(k_attn, dim3(B * IT * 2), dim3(1024), 0, stream, adjb, h_frag, el, er, pnum, pden);
  hipLaunchKernelGGL(k_final, dim3(B * IT), dim3(1024), 0, stream, pnum, pden, out);
}

// Round 8
// 127.111 us; speedup vs baseline: 1.5207x; 1.0363x over previous
//
#include <hip/hip_runtime.h>
#include <stdint.h>

#define LOG2E 1.4426950408889634f

typedef __bf16 v8bf __attribute__((ext_vector_type(8)));
typedef float v16f __attribute__((ext_vector_type(16)));

static constexpr int B = 4, N = 2048, FIN = 128, H = 4, DK = 32;
static constexpr int IT = N / 32;   // 64 i-tiles
static constexpr int PACK_BLOCKS = B * N * N / 1024;          // 16384
static constexpr int PREP_BLOCKS = (B * N * FIN + H * DK * FIN) / 256;  // 4160

__device__ __forceinline__ float exp2_fast(float x) {
#if __has_builtin(__builtin_amdgcn_exp2f)
  return __builtin_amdgcn_exp2f(x);
#else
  float r;
  asm("v_exp_f32 %0, %1" : "=v"(r) : "v"(x));
  return r;
#endif
}

__device__ __forceinline__ unsigned int bf16_rne(float f) {
  unsigned int u = __builtin_bit_cast(unsigned int, f);
  u += 0x7FFFu + ((u >> 16) & 1u);
  return u >> 16;
}

// ------- kernel 0 (merged): adj bit-pack + x->bf16 cast + wtb[h][d][f] bf16 -------
__global__ __launch_bounds__(256) void k_prep(const int* __restrict__ adj,
                                              const float* __restrict__ x,
                                              const float* __restrict__ W,
                                              unsigned int* __restrict__ adjb,
                                              unsigned short* __restrict__ xb,
                                              unsigned short* __restrict__ wtb) {
  int bid = blockIdx.x;
  int tid = threadIdx.x;
  if (bid < PACK_BLOCKS) {
    int wid = (bid * 256 + tid) >> 6;      // global wave id, 256 consecutive ints each
    int lane = tid & 63;
    const int* p = adj + (size_t)wid * 256 + lane;
    unsigned long long m0 = __ballot(p[0] != 0);
    unsigned long long m1 = __ballot(p[64] != 0);
    unsigned long long m2 = __ballot(p[128] != 0);
    unsigned long long m3 = __ballot(p[192] != 0);
    if (lane == 0) {
      uint4 v0 = {(unsigned)m0, (unsigned)(m0 >> 32), (unsigned)m1, (unsigned)(m1 >> 32)};
      uint4 v1 = {(unsigned)m2, (unsigned)(m2 >> 32), (unsigned)m3, (unsigned)(m3 >> 32)};
      uint4* dst = (uint4*)(adjb + (size_t)wid * 8);
      dst[0] = v0;
      dst[1] = v1;
    }
    return;
  }
  int idx = (bid - PACK_BLOCKS) * 256 + tid;
  constexpr int TX = B * N * FIN;          // 1048576
  if (idx < TX) {
    xb[idx] = (unsigned short)bf16_rne(x[idx]);
  } else {
    int j = idx - TX;                      // < H*DK*FIN = 16384
    int h = j >> 12, r = j & 4095, d = r >> 7, f = r & 127;
    wtb[j] = (unsigned short)bf16_rne(W[(h * FIN + f) * DK + d]);
  }
}

// ------- kernel 1: h projection via dual MFMA; h_frag (fragment order) + el/er2/fr2 -------
// er2 = exp2(er*log2e), fr2 = exp2(0.2*er*log2e): j-side softmax-product tables.
__global__ __launch_bounds__(256) void k_hproj(const unsigned short* __restrict__ xb,
                                               const unsigned short* __restrict__ wtb,
                                               const float* __restrict__ a,
                                               unsigned short* __restrict__ h_frag,
                                               float* __restrict__ el,
                                               float* __restrict__ er2,
                                               float* __restrict__ fr2) {
  int blk = blockIdx.x;
  int b = blk >> 6, it = blk & 63;
  int tid = threadIdx.x;
  int head = tid >> 6, lane = tid & 63;
  int lrow = lane & 31, kh = lane >> 5;
  int bh = b * H + head;
  int n = it * 32 + lrow;
  const unsigned short* xp = xb + (b * N + n) * FIN + kh * 8;
  const unsigned short* wp = wtb + (head * DK + lrow) * FIN + kh * 8;
  v16f acc = {};    // D[d][n], col=n=lrow
  v16f accd = {};   // D[n][d], col=d=lrow
#pragma unroll
  for (int s = 0; s < FIN / 16; ++s) {
    v8bf av = __builtin_bit_cast(v8bf, *(const int4*)(wp + s * 16));
    v8bf bv = __builtin_bit_cast(v8bf, *(const int4*)(xp + s * 16));
    acc = __builtin_amdgcn_mfma_f32_32x32x16_bf16(av, bv, acc, 0, 0, 0);
    accd = __builtin_amdgcn_mfma_f32_32x32x16_bf16(bv, av, accd, 0, 0, 0);
  }
  // h_frag: thread holds h[n = (r&3)+8*(r>>2)+4*kh][d = lrow] for r=0..15.
  {
    unsigned w[8];
#pragma unroll
    for (int i = 0; i < 8; ++i)
      w[i] = bf16_rne(accd[2 * i]) | (bf16_rne(accd[2 * i + 1]) << 16);
    unsigned short* fp = h_frag + (((size_t)bh * 128 + it * 2) * 64 + lane) * 8;
    int4 v0 = {(int)w[0], (int)w[1], (int)w[2], (int)w[3]};
    int4 v1 = {(int)w[4], (int)w[5], (int)w[6], (int)w[7]};
    *(int4*)fp = v0;
    *(int4*)(fp + 512) = v1;   // next jblk: +64 lanes * 8 shorts
  }
  float pel = 0.f, per = 0.f;
#pragma unroll
  for (int r = 0; r < 16; ++r) {
    int d = (r & 3) + 8 * (r >> 2) + 4 * kh;   // C/D row mapping (32x32 bf16)
    float hv = acc[r];
    pel = fmaf(hv, a[head * 2 * DK + d], pel);
    per = fmaf(hv, a[head * 2 * DK + DK + d], per);
  }
  pel += __shfl_xor(pel, 32);
  per += __shfl_xor(per, 32);
  if (kh == 0) {
    el[bh * N + n] = pel * LOG2E;
    float t = per * LOG2E;
    er2[bh * N + n] = exp2_fast(t);
    fr2[bh * N + n] = exp2_fast(0.2f * t);
  }
}

// ---------------- kernel 2: fused attention over a j-QUARTER ----------------
// grid = B*IT*4 = 1024; block = 512 threads = 8 waves = (kq 0..1) x (head 0..3)
// launch_bounds(512,4): 128-VGPR budget (no spill, r7 lesson) AND 2 blocks/CU
// resident -> one block's loop overlaps the other's prologue/epilogue convoy.
// Inner loop exp-free: exp2(max(t,.2t)) == max(Eli*er2[j], Fli*fr2[j]) (monotone).
__global__ __launch_bounds__(512, 4) void k_attn(const unsigned int* __restrict__ adjb,
                                                 const unsigned short* __restrict__ h_frag,
                                                 const float* __restrict__ el,
                                                 const float* __restrict__ er2,
                                                 const float* __restrict__ fr2,
                                                 float* __restrict__ pnum,
                                                 float* __restrict__ pden) {
  __shared__ __align__(16) float part2[2][H][1024];  // 32KB; first 16KB aliased as stage
  __shared__ float lsh2[2][H][32];
  float(*stg)[H][512] = (float(*)[H][512]) & part2[0][0][0];  // stg[0]=er2, stg[1]=fr2
  int blk = blockIdx.x;                 // 0..1023
  int bit = blk >> 2, jQ = blk & 3;
  int b = bit >> 6, it = bit & 63;
  int tid = threadIdx.x;
  int wave = tid >> 6;
  int head = wave & 3, kq = wave >> 2;
  int lane = tid & 63, lrow = lane & 31, kh = lane >> 5;
  int ig = it * 32 + lrow, bh = b * H + head;

  // stage this quarter's er2/fr2 for all 4 heads: 2*2048 floats, 2 float4/thread
  {
    int hh = tid >> 7, jl = (tid & 127) * 4;
    int base = (b * H + hh) * N + jQ * 512 + jl;
    *(float4*)&stg[0][hh][jl] = *(const float4*)&er2[base];
    *(float4*)&stg[1][hh][jl] = *(const float4*)&fr2[base];
  }

  float eli = el[bh * N + ig];
  float Eli = exp2_fast(eli);
  float Fli = exp2_fast(0.2f * eli);

  // coalesced fragment pointer: jblk = jQ*32 + kq*16 + s ; 512 shorts per s
  const unsigned short* hp =
      h_frag + (((size_t)bh * 128 + jQ * 32 + kq * 16) * 64 + lane) * 8;
  int jql = kq * 256 + 4 * kh;          // j-local base into stage (k-permuted)

  // adjacency bits for this lane's 256-j window
  const uint4* abp = (const uint4*)(adjb + (size_t)(b * N + ig) * 64 + jQ * 16 + kq * 8);
  uint4 ab0 = abp[0], ab1 = abp[1];
  unsigned adw[8] = {ab0.x, ab0.y, ab0.z, ab0.w, ab1.x, ab1.y, ab1.z, ab1.w};
  int shkh = kh * 4;

  // h prefetch, 2 deep (global, no LDS dependency)
  int4 hreg0 = *(const int4*)hp;
  int4 hreg1 = *(const int4*)(hp + 512);

  __syncthreads();   // stage visible

  v16f acc = {};
  float lsum = 0.f;
  float4 Ea = *(const float4*)&stg[0][head][jql];
  float4 Eb = *(const float4*)&stg[0][head][jql + 8];
  float4 Fa = *(const float4*)&stg[1][head][jql];
  float4 Fb = *(const float4*)&stg[1][head][jql + 8];
#pragma unroll
  for (int s = 0; s < 16; ++s) {
    int4 hb = (s & 1) ? hreg1 : hreg0;
    if (s + 2 < 16) {
      int4 nv = *(const int4*)(hp + (s + 2) * 512);
      if (s & 1) hreg1 = nv; else hreg0 = nv;
    }
    float4 ea = Ea, eb = Eb, fa = Fa, fb = Fb;
    if (s + 1 < 16) {
      Ea = *(const float4*)&stg[0][head][jql + (s + 1) * 16];
      Eb = *(const float4*)&stg[0][head][jql + (s + 1) * 16 + 8];
      Fa = *(const float4*)&stg[1][head][jql + (s + 1) * 16];
      Fb = *(const float4*)&stg[1][head][jql + (s + 1) * 16 + 8];
    }
    // bits for slots e: j-offset = s*16 + 4*kh + (e&3) + 8*(e>>2)
    unsigned mb = (adw[s >> 1] >> (((s & 1) * 16) + shkh)) & 0xF0Fu;
    float ev[8] = {ea.x, ea.y, ea.z, ea.w, eb.x, eb.y, eb.z, eb.w};
    float fv[8] = {fa.x, fa.y, fa.z, fa.w, fb.x, fb.y, fb.z, fb.w};
    unsigned ub[8];
#pragma unroll
    for (int k = 0; k < 8; ++k) {
      float pv = fmaxf(Eli * ev[k], Fli * fv[k]);   // leaky-relu+exp, product form
      unsigned u = __builtin_bit_cast(unsigned, pv) & 0xFFFF0000u;
      // compile-time constant bit (k unrolled): {1,2,4,8,0x100,0x200,0x400,0x800}
      u = (mb & (1u << ((k & 3) + 8 * (k >> 2)))) ? u : 0u;
      ub[k] = u;
      lsum += __builtin_bit_cast(float, u); // truncated value: num/den consistent
    }
    unsigned u0 = __builtin_amdgcn_perm(ub[1], ub[0], 0x07060302u);
    unsigned u1 = __builtin_amdgcn_perm(ub[3], ub[2], 0x07060302u);
    unsigned u2 = __builtin_amdgcn_perm(ub[5], ub[4], 0x07060302u);
    unsigned u3 = __builtin_amdgcn_perm(ub[7], ub[6], 0x07060302u);
    uint4 au = {u0, u1, u2, u3};
    v8bf av = __builtin_bit_cast(v8bf, au);
    v8bf hv = __builtin_bit_cast(v8bf, hb);
    acc = __builtin_amdgcn_mfma_f32_32x32x16_bf16(av, hv, acc, 0, 0, 0);
  }

  lsum += __shfl_xor(lsum, 32);
  if (lane < 32) lsh2[kq][head][lane] = lsum;   // separate array: safe pre-barrier

  __syncthreads();   // all stage LDS reads done before part2 overwrite

#pragma unroll
  for (int r = 0; r < 16; ++r) {
    int rowl = (r & 3) + 8 * (r >> 2) + 4 * kh;   // i-row within tile
    part2[kq][head][rowl * 32 + lrow] = acc[r];   // private slice: plain store
  }
  __syncthreads();

  // combine 2 kq slices; 4096 partials / 512 threads = 8 floats (2x float4) each
  int e = tid * 8;
  int rh = e >> 10, rr = e & 1023;
  float4 a0 = *(const float4*)&part2[0][rh][rr];
  float4 a1 = *(const float4*)&part2[1][rh][rr];
  float4 b0 = *(const float4*)&part2[0][rh][rr + 4];
  float4 b1 = *(const float4*)&part2[1][rh][rr + 4];
  float4 s0 = {a0.x + a1.x, a0.y + a1.y, a0.z + a1.z, a0.w + a1.w};
  float4 s1 = {b0.x + b1.x, b0.y + b1.y, b0.z + b1.z, b0.w + b1.w};
  *(float4*)&pnum[(size_t)blk * 4096 + e] = s0;
  *(float4*)&pnum[(size_t)blk * 4096 + e + 4] = s1;
  if (tid < 128) {
    pden[blk * 128 + tid] = lsh2[0][tid >> 5][tid & 31] + lsh2[1][tid >> 5][tid & 31];
  }
}

// ---------------- kernel 3: combine 4 j-quarters + normalize ----------------
__global__ __launch_bounds__(1024) void k_final(const float* __restrict__ pnum,
                                                const float* __restrict__ pden,
                                                float* __restrict__ out) {
  int bit = blockIdx.x;            // 0..255 = (b, it)
  int b = bit >> 6, it = bit & 63;
  int tid = threadIdx.x;
  int e = tid * 4;
  int rh = e >> 10, ri = (e >> 5) & 31, rd = e & 31;
  size_t p0 = (size_t)(bit * 4) * 4096 + e;
  float4 n0 = *(const float4*)&pnum[p0];
  float4 n1 = *(const float4*)&pnum[p0 + 4096];
  float4 n2 = *(const float4*)&pnum[p0 + 2 * 4096];
  float4 n3 = *(const float4*)&pnum[p0 + 3 * 4096];
  int dbase = bit * 4 * 128 + rh * 32 + ri;
  float d = (pden[dbase] + pden[dbase + 128]) + (pden[dbase + 256] + pden[dbase + 384]);
  float inv = 1.0f / d;
  float4 o;
  o.x = ((n0.x + n1.x) + (n2.x + n3.x)) * inv;
  o.y = ((n0.y + n1.y) + (n2.y + n3.y)) * inv;
  o.z = ((n0.z + n1.z) + (n2.z + n3.z)) * inv;
  o.w = ((n0.w + n1.w) + (n2.w + n3.w)) * inv;
  *(float4*)&out[(size_t)((b * H + rh) * N + it * 32 + ri) * DK + rd] = o;
}

extern "C" void kernel_launch(void* const* d_in, const int* in_sizes, int n_in,
                              void* d_out, int out_size, void* d_ws, size_t ws_size,
                              hipStream_t stream) {
  const float* x = (const float*)d_in[0];
  const int* adj = (const int*)d_in[1];
  const float* W = (const float*)d_in[2];
  const float* a = (const float*)d_in[3];
  float* out = (float*)d_out;
  char* ws = (char*)d_ws;

  unsigned short* h_frag = (unsigned short*)(ws);          // 2 MB   [B*H][128 jblk][64][8]
  float* el = (float*)(ws + 0x200000);                     // 128 KB
  float* er2 = (float*)(ws + 0x220000);                    // 128 KB exp2 table
  float* fr2 = (float*)(ws + 0x240000);                    // 128 KB exp2(0.2) table
  unsigned short* wtb = (unsigned short*)(ws + 0x260000);  // 32 KB
  unsigned int* adjb = (unsigned int*)(ws + 0x270000);     // 2 MB bitmask
  unsigned short* xb = (unsigned short*)(ws + 0x470000);   // 2 MB
  float* pnum = (float*)(ws + 0x670000);                   // 16 MB  [1024][4096]
  float* pden = (float*)(ws + 0x1670000);                  // 512 KB [1024][128]
  // total ~23 MB

  hipLaunchKernelGGL(k_prep, dim3(PACK_BLOCKS + PREP_BLOCKS), dim3(256), 0, stream,
                     adj, x, W, adjb, xb, wtb);
  hipLaunchKernelGGL(k_hproj, dim3(B * IT), dim3(256), 0, stream, xb, wtb, a, h_frag, el, er2, fr2);
  hipLaunchKernelGGL(k_attn, dim3(B * IT * 4), dim3(512), 0, stream, adjb, h_frag, el, er2, fr2,
                     pnum, pden);
  hipLaunchKernelGGL(k_final, dim3(B * IT), dim3(1024), 0, stream, pnum, pden, out);
}